// Round 7
// baseline (131.254 us; speedup 1.0000x reference)
//
#include <hip/hip_runtime.h>
#include <math.h>

// MPS-RNN 2D forward: L=8, M=8, DCUT=6, HL=2, N=64, B=32768
// 4 lanes/sample. Round-7: snake-ordered chunk-resident params (all LDS
// offsets compile-time immediates), hv prefetch + row-boundary bypass,
// Mh/Mv interleaved b128 reads, eta^2 staged, amp^2 + raw rcp/rsq.

#define MCOLS 8
#define DC    6
#define NQ    64
#define BT    256
#define SPB   64

// LDS float offsets (16-site chunk, snake-slot order)
#define TL     0      // T:   [16][12][36]
#define MHVL   6912   // MhMv interleaved: [16][12][12] (6 mh | 6 mv)
#define VL     9216   // [16][12]
#define WL     9408   // [16][6]
#define EL     9504   // eta^2: [16][6]
#define CL     9600   // [16]
#define PARAM_F 9616
#define VS_STRIDE 68  // per-sample vertical state: 8 cols x 8 floats + pad

#if defined(__has_builtin)
#  if __has_builtin(__builtin_amdgcn_rcpf)
#    define FAST_RCP(x) __builtin_amdgcn_rcpf(x)
#  else
#    define FAST_RCP(x) (1.0f / (x))
#  endif
#  if __has_builtin(__builtin_amdgcn_rsqf)
#    define FAST_RSQ(x) __builtin_amdgcn_rsqf(x)
#  else
#    define FAST_RSQ(x) rsqrtf(x)
#  endif
#else
#  define FAST_RCP(x) (1.0f / (x))
#  define FAST_RSQ(x) rsqrtf(x)
#endif

__global__ __launch_bounds__(BT, 1) void mps_rnn7(
    const float* __restrict__ Mh,   // (L,M,2,6,6)
    const float* __restrict__ Mv,   // (L,M,2,6,6)
    const float* __restrict__ Vp,   // (L,M,2,6)
    const float* __restrict__ Tp,   // (L,M,2,6,6,6)
    const float* __restrict__ Wp,   // (L,M,6)
    const float* __restrict__ Cp,   // (L,M)
    const float* __restrict__ Ep,   // (L,M,6)
    const int*   __restrict__ X,    // (B,64)
    float*       __restrict__ out,
    int Bn, int writeImag)
{
    __shared__ float ps[PARAM_F];
    __shared__ float vs[SPB * VS_STRIDE];

    const int t   = threadIdx.x;
    const int sub = t & 3;
    const int s   = t >> 2;
    int b = blockIdx.x * SPB + s;
    const bool valid = (b < Bn);
    if (!valid) b = Bn - 1;          // clamp loads; no early return (barriers!)

    // cooperative bit pack
    unsigned long long bits;
    {
        const int4* xr = reinterpret_cast<const int4*>(X + (size_t)b * NQ + sub * 16);
        unsigned long long part = 0ull;
        #pragma unroll
        for (int q = 0; q < 4; ++q) {
            int4 v = xr[q];
            part |= (unsigned long long)(v.x & 1) << (4 * q + 0);
            part |= (unsigned long long)(v.y & 1) << (4 * q + 1);
            part |= (unsigned long long)(v.z & 1) << (4 * q + 2);
            part |= (unsigned long long)(v.w & 1) << (4 * q + 3);
        }
        bits = part << (16 * sub);
        bits |= __shfl_xor(bits, 1, 64);
        bits |= __shfl_xor(bits, 2, 64);
    }

    for (int u = t; u < SPB * VS_STRIDE; u += BT) vs[u] = 0.f;

    const int r0    = sub * 3;       // row base (rows r0..r0+2 of 12)
    const int mya   = sub >> 1;
    const int ohi   = sub & 1;
    const int lbase = (t & 63) & ~3;
    float* vsp = vs + s * VS_STRIDE;

    float hh[6], hv[6];
    #pragma unroll
    for (int o = 0; o < 6; ++o) hv[o] = 0.f;   // bottom boundary
    float amp2 = 1.f, phi = 0.f;

    for (int ch = 0; ch < 4; ++ch) {
        __syncthreads();             // previous chunk fully consumed
        // ---- stage chunk ch (sites 16ch..16ch+15) in snake-slot order
        {
            const float4* gT = reinterpret_cast<const float4*>(Tp) + ch * 1728;
            float4* lT = reinterpret_cast<float4*>(ps + TL);
            for (int u = t; u < 1728; u += BT) {
                int sc = u / 108, w = u - sc * 108;
                int slot = (sc < 8) ? sc : 23 - sc;
                lT[slot * 108 + w] = gT[u];
            }
            const float2* gH = reinterpret_cast<const float2*>(Mh) + ch * 576;
            const float2* gV = reinterpret_cast<const float2*>(Mv) + ch * 576;
            float2* lHV = reinterpret_cast<float2*>(ps + MHVL);
            for (int u = t; u < 576; u += BT) {
                int sc = u / 36, w = u - sc * 36;
                int row = w / 3, p = w - row * 3;
                int slot = (sc < 8) ? sc : 23 - sc;
                lHV[slot * 72 + row * 6 + p]     = gH[u];
                lHV[slot * 72 + row * 6 + 3 + p] = gV[u];
            }
            if (t < 48) {
                int sc = t / 3, w = t - sc * 3;
                int slot = (sc < 8) ? sc : 23 - sc;
                reinterpret_cast<float4*>(ps + VL)[slot * 3 + w] =
                    reinterpret_cast<const float4*>(Vp)[ch * 48 + t];
            } else if (t < 96) {
                int u = t - 48; int sc = u / 3, w = u - sc * 3;
                int slot = (sc < 8) ? sc : 23 - sc;
                reinterpret_cast<float2*>(ps + WL)[slot * 3 + w] =
                    reinterpret_cast<const float2*>(Wp)[ch * 48 + u];
            } else if (t < 144) {
                int u = t - 96; int sc = u / 3, w = u - sc * 3;
                int slot = (sc < 8) ? sc : 23 - sc;
                float2 e = reinterpret_cast<const float2*>(Ep)[ch * 48 + u];
                e.x *= e.x; e.y *= e.y;
                reinterpret_cast<float2*>(ps + EL)[slot * 3 + w] = e;
            } else if (t < 160) {
                int u = t - 144;
                int slot = (u < 8) ? u : 23 - u;
                ps[CL + slot] = Cp[ch * 16 + u];
            }
        }
        __syncthreads();             // chunk visible

        #pragma unroll
        for (int ih = 0; ih < 2; ++ih) {
            const float4* T4  = reinterpret_cast<const float4*>(ps + TL)   + ih * 864 + r0 * 9;
            const float4* HV4 = reinterpret_cast<const float4*>(ps + MHVL) + ih * 288 + r0 * 3;
            const float* Vb = ps + VL + ih * 96 + r0;
            const float* Wb = ps + WL + ih * 48;
            const float* Eb = ps + EL + ih * 48 + ohi * 3;
            const float* Cb = ps + CL + ih * 8;
            const unsigned cbr = (unsigned)(bits >> (ch * 16 + ih * 8)) & 0xFFu;

            #pragma unroll
            for (int q = 0; q < 8; ++q) {
                const int jrow = ih ? 7 - q : q;     // this step's column

                // prefetch next column's vertical state (written a row ago;
                // same wave -> ordered; different column -> no hazard)
                float hvn[6] = {0,0,0,0,0,0};
                if (q < 7) {
                    const int jn = ih ? 6 - q : q + 1;
                    float4 h03 = *reinterpret_cast<const float4*>(vsp + jn * 8);
                    float2 h45 = *reinterpret_cast<const float2*>(vsp + jn * 8 + 4);
                    hvn[0]=h03.x; hvn[1]=h03.y; hvn[2]=h03.z; hvn[3]=h03.w;
                    hvn[4]=h45.x; hvn[5]=h45.y;
                }

                if (q == 0) {                         // left boundary
                    #pragma unroll
                    for (int o = 0; o < 6; ++o) hh[o] = 1.f;
                }

                float vv[3], e2[3];
                #pragma unroll
                for (int lr = 0; lr < 3; ++lr) {
                    vv[lr] = Vb[q * 12 + lr];
                    e2[lr] = Eb[q * 6 + lr];
                }
                float wf[6];
                {
                    float2 w01 = *reinterpret_cast<const float2*>(Wb + q * 6);
                    float2 w23 = *reinterpret_cast<const float2*>(Wb + q * 6 + 2);
                    float2 w45 = *reinterpret_cast<const float2*>(Wb + q * 6 + 4);
                    wf[0]=w01.x; wf[1]=w01.y; wf[2]=w23.x; wf[3]=w23.y; wf[4]=w45.x; wf[5]=w45.y;
                }
                const float ck = Cb[q];

                float acc[3];
                #pragma unroll
                for (int lr = 0; lr < 3; ++lr) {
                    float tf[36];
                    #pragma unroll
                    for (int p = 0; p < 9; ++p) {
                        float4 x = T4[q * 108 + lr * 9 + p];
                        tf[4*p]=x.x; tf[4*p+1]=x.y; tf[4*p+2]=x.z; tf[4*p+3]=x.w;
                    }
                    float4 m0 = HV4[q * 36 + lr * 3 + 0];
                    float4 m1 = HV4[q * 36 + lr * 3 + 1];
                    float4 m2 = HV4[q * 36 + lr * 3 + 2];
                    const float mh0=m0.x, mh1=m0.y, mh2=m0.z, mh3=m0.w, mh4=m1.x, mh5=m1.y;
                    const float mv0=m1.z, mv1=m1.w, mv2=m2.x, mv3=m2.y, mv4=m2.z, mv5=m2.w;

                    const float hho = ohi ? hh[lr + 3] : hh[lr];
                    const float hvo = ohi ? hv[lr + 3] : hv[lr];
                    const float base = vv[lr] + hho + hvo;

                    float sc6[6];
                    #pragma unroll
                    for (int c = 0; c < 6; ++c) {
                        const int o0 = c * 6;
                        float sa = fmaf(tf[o0+0], hv[0], fmaf(tf[o0+2], hv[2], tf[o0+4]*hv[4]));
                        float sb = fmaf(tf[o0+1], hv[1], fmaf(tf[o0+3], hv[3], tf[o0+5]*hv[5]));
                        sc6[c] = sa + sb;
                    }
                    float p0 = fmaf(sc6[0], hh[0], fmaf(sc6[3], hh[3], base));
                    float p1 = fmaf(sc6[1], hh[1], sc6[4] * hh[4]);
                    float p2 = fmaf(sc6[2], hh[2], sc6[5] * hh[5]);
                    float ma = fmaf(mh0, hh[0], fmaf(mh2, hh[2], mh4*hh[4]));
                    float mb = fmaf(mh1, hh[1], fmaf(mh3, hh[3], mh5*hh[5]));
                    float na = fmaf(mv0, hv[0], fmaf(mv2, hv[2], mv4*hv[4]));
                    float nb = fmaf(mv1, hv[1], fmaf(mv3, hv[3], mv5*hv[5]));
                    acc[lr] = ((p0 + p1) + (p2 + ma)) + ((mb + na) + nb);
                }

                // 4-lane reductions on unnormalized acc (inv^2 cancels in prob)
                float a2[3];
                #pragma unroll
                for (int lr = 0; lr < 3; ++lr) a2[lr] = acc[lr] * acc[lr];
                float ssl = (a2[0] + a2[1]) + a2[2];
                float pq  = fmaf(e2[0], a2[0], fmaf(e2[1], a2[1], e2[2] * a2[2]));
                ssl += __shfl_xor(ssl, 1, 64);
                pq  += __shfl_xor(pq,  1, 64);
                const float ssq = ssl + __shfl_xor(ssl, 2, 64);
                const float pqx = __shfl_xor(pq, 2, 64);
                const float inv = FAST_RSQ(ssq + 1e-12f);

                const int sel = (cbr >> q) & 1;
                const float qsel = (mya == sel) ? pq : pqx;
                amp2 *= qsel * FAST_RCP(pq + pqx);

                const int s0 = lbase + 2 * sel;
                const int s1 = s0 + 1;
                hh[0] = __shfl(acc[0], s0, 64) * inv;
                hh[1] = __shfl(acc[1], s0, 64) * inv;
                hh[2] = __shfl(acc[2], s0, 64) * inv;
                hh[3] = __shfl(acc[0], s1, 64) * inv;
                hh[4] = __shfl(acc[1], s1, 64) * inv;
                hh[5] = __shfl(acc[2], s1, 64) * inv;

                float ph = ck;
                #pragma unroll
                for (int o = 0; o < 6; ++o) ph = fmaf(wf[o], hh[o], ph);
                phi += ph;

                if (sub == 0) {
                    *reinterpret_cast<float4*>(vsp + jrow * 8) =
                        make_float4(hh[0], hh[1], hh[2], hh[3]);
                    *reinterpret_cast<float2*>(vsp + jrow * 8 + 4) =
                        make_float2(hh[4], hh[5]);
                }

                // advance vertical state: row end -> same column next row (bypass)
                if (q == 7) {
                    #pragma unroll
                    for (int o = 0; o < 6; ++o) hv[o] = hh[o];
                } else {
                    #pragma unroll
                    for (int o = 0; o < 6; ++o) hv[o] = hvn[o];
                }
            }
        }
    }

    if (sub == 0 && valid) {
        const float amp = sqrtf(amp2);
        if (writeImag) {
            out[2 * b + 0] = amp * cosf(phi);
            out[2 * b + 1] = amp * sinf(phi);
        } else {
            out[b] = amp * cosf(phi);
        }
    }
}

extern "C" void kernel_launch(void* const* d_in, const int* in_sizes, int n_in,
                              void* d_out, int out_size, void* d_ws, size_t ws_size,
                              hipStream_t stream) {
    const float* Mh = (const float*)d_in[0];
    const float* Mv = (const float*)d_in[1];
    const float* Vp = (const float*)d_in[2];
    const float* Tp = (const float*)d_in[3];
    const float* Wp = (const float*)d_in[4];
    const float* Cp = (const float*)d_in[5];
    const float* Ep = (const float*)d_in[6];
    const int*   X  = (const int*)d_in[7];
    float* out = (float*)d_out;

    const int Bn = in_sizes[7] / NQ;                 // 32768
    const int writeImag = (out_size >= 2 * Bn) ? 1 : 0;
    const int grid = (Bn + SPB - 1) / SPB;           // 512 blocks of 256 threads

    mps_rnn7<<<grid, BT, 0, stream>>>(Mh, Mv, Vp, Tp, Wp, Cp, Ep, X, out,
                                      Bn, writeImag);
}